// Round 8
// baseline (190.416 us; speedup 1.0000x reference)
//
#include <hip/hip_runtime.h>
#include <hip/hip_bf16.h>
#include <math.h>

#define BATCH  2
#define S_LEN  2048
#define DMODEL 1024
#define NH     16
#define DHEAD  64

typedef __attribute__((ext_vector_type(8))) short bf16x8;   // 8 bf16 = 4 VGPRs
typedef __attribute__((ext_vector_type(4))) float f32x4;

#define MFMA16(a,b,c) __builtin_amdgcn_mfma_f32_16x16x32_bf16((a),(b),(c),0,0,0)

// Q pre-scale: (1/sqrt(64)) * log2(e) so attention uses exp2 directly
#define QSCALE 0.18033688011110793f
#define EXP2F(x) __builtin_amdgcn_exp2f(x)

__device__ __forceinline__ unsigned int pkbf(float a, float b) {
    __hip_bfloat162 h = __float22bfloat162_rn(make_float2(a, b));
    union { __hip_bfloat162 h; unsigned int u; } v; v.h = h; return v.u;
}

// ---------------------------------------------------------------------------
// Single fused fp32->bf16 convert for Q, W_Q|W_K|W_V, mask. 8 elems/unit.
// ---------------------------------------------------------------------------
__global__ __launch_bounds__(256) void cvt_all(
    const float* __restrict__ Q,  const float* __restrict__ WQ,
    const float* __restrict__ WK, const float* __restrict__ WV,
    const float* __restrict__ msk,
    unsigned short* __restrict__ Qbf, unsigned short* __restrict__ Wbf,
    unsigned short* __restrict__ mbf)
{
    int i = blockIdx.x * blockDim.x + threadIdx.x;   // grid covers 918016 units
    const float* src;
    unsigned short* dst;
    int off;
    if (i < 524288) {
        src = Q; dst = Qbf; off = i;
    } else if (i < 917504) {
        int j = i - 524288;                  // [0, 393216)
        int which = j >> 17;                 // /131072
        src = (which == 0) ? WQ : ((which == 1) ? WK : WV);
        dst = Wbf + ((size_t)which << 20);   // which * 1048576
        off = j & 131071;
    } else {
        int j = i - 917504;
        if (j >= 512) return;
        src = msk; dst = mbf; off = j;
    }
    float4 a = ((const float4*)src)[2*off];
    float4 b = ((const float4*)src)[2*off + 1];
    uint4 o;
    o.x = pkbf(a.x, a.y); o.y = pkbf(a.z, a.w);
    o.z = pkbf(b.x, b.y); o.w = pkbf(b.z, b.w);
    ((uint4*)dst)[off] = o;
}

// ---------------------------------------------------------------------------
// Projection GEMM with folds:
//   z=0 -> qw [b,h,s,dk], scaled by QSCALE; z=1 -> kw; z=2 -> vt [b,h,dv,s]
//   with V' = mask*V.
// 128x128 tile, BK=32, 4 waves. K-loop: register prefetch + double-buffered
// LDS + ONE barrier per iteration (loads for t+1 in flight across compute t).
// Epilogue through LDS (aliases staging) for 128B-contiguous stores.
// ---------------------------------------------------------------------------
__global__ __launch_bounds__(256) void proj_mfma(
    const unsigned short* __restrict__ Abf,   // [4096][1024]
    const unsigned short* __restrict__ Wbf,   // [3][1024][1024]
    const float* __restrict__ bQ, const float* __restrict__ bK,
    const float* __restrict__ bV, const float* __restrict__ mask,
    unsigned short* __restrict__ qw, unsigned short* __restrict__ kw,
    unsigned short* __restrict__ vt)
{
    __shared__ union {
        struct { unsigned short A[2][4096]; unsigned short B[2][4096]; } s; // 32KB
        unsigned short Ct[128*132];                                         // 33.8KB
    } sm;

    const int tid  = threadIdx.x;
    const int lane = tid & 63;
    const int wv   = tid >> 6;
    const int wm   = (wv >> 1) * 64;
    const int wn   = (wv & 1) * 64;
    const int q15  = lane & 15;
    const int quad = lane >> 4;
    const int z    = blockIdx.z;
    const int n0   = blockIdx.x * 128;
    const int m0   = blockIdx.y * 128;

    const unsigned short* Wz = Wbf + (size_t)z * DMODEL * DMODEL;
    const float* bias = (z == 0) ? bQ : ((z == 1) ? bK : bV);

    // staging map: tile = 128 rows x 32 cols bf16 = 512 uint4; thread t
    // handles uint4 f = t and t+256: row = f>>2, col8 = (f&3)*8 shorts.
    const int r0 = tid >> 2,          c0 = (tid & 3) * 8;
    const int r1 = (tid + 256) >> 2,  c1 = c0;   // f&3 identical

    f32x4 zero4 = {0.f, 0.f, 0.f, 0.f};
    f32x4 acc[4][4];
    #pragma unroll
    for (int i = 0; i < 4; ++i)
        #pragma unroll
        for (int j = 0; j < 4; ++j) acc[i][j] = zero4;

    // prologue: prefetch k0=0 tiles into registers
    uint4 a0, a1, b0, b1;
    a0 = *(const uint4*)(Abf + (size_t)(m0 + r0) * DMODEL + c0);
    a1 = *(const uint4*)(Abf + (size_t)(m0 + r1) * DMODEL + c1);
    b0 = *(const uint4*)(Wz  + (size_t)(n0 + r0) * DMODEL + c0);
    b1 = *(const uint4*)(Wz  + (size_t)(n0 + r1) * DMODEL + c1);

    for (int t = 0; t < 32; ++t) {
        const int buf = t & 1;
        // commit prefetched regs to LDS[buf]
        *(uint4*)(sm.s.A[buf] + r0*32 + c0) = a0;
        *(uint4*)(sm.s.A[buf] + r1*32 + c1) = a1;
        *(uint4*)(sm.s.B[buf] + r0*32 + c0) = b0;
        *(uint4*)(sm.s.B[buf] + r1*32 + c1) = b1;
        // issue prefetch for tile t+1 (clamped; overlaps compute below)
        const int kn = (t < 31) ? (t + 1) * 32 : 0;
        a0 = *(const uint4*)(Abf + (size_t)(m0 + r0) * DMODEL + kn + c0);
        a1 = *(const uint4*)(Abf + (size_t)(m0 + r1) * DMODEL + kn + c1);
        b0 = *(const uint4*)(Wz  + (size_t)(n0 + r0) * DMODEL + kn + c0);
        b1 = *(const uint4*)(Wz  + (size_t)(n0 + r1) * DMODEL + kn + c1);
        __syncthreads();   // single barrier: commits visible, prev reads done

        bf16x8 af[4], bf[4];
        #pragma unroll
        for (int i = 0; i < 4; ++i)
            af[i] = *(const bf16x8*)(sm.s.A[buf] + (wm + i*16 + q15) * 32 + quad * 8);
        #pragma unroll
        for (int j = 0; j < 4; ++j)
            bf[j] = *(const bf16x8*)(sm.s.B[buf] + (wn + j*16 + q15) * 32 + quad * 8);

        if (z < 2) {
            #pragma unroll
            for (int i = 0; i < 4; ++i)
                #pragma unroll
                for (int j = 0; j < 4; ++j)
                    acc[i][j] = MFMA16(bf[j], af[i], acc[i][j]);
        } else {
            #pragma unroll
            for (int i = 0; i < 4; ++i)
                #pragma unroll
                for (int j = 0; j < 4; ++j)
                    acc[i][j] = MFMA16(af[i], bf[j], acc[i][j]);
        }
    }

    __syncthreads();   // all compute reads done; Ct aliases staging

    if (z < 2) {
        const float qs = (z == 0) ? QSCALE : 1.0f;
        #pragma unroll
        for (int i = 0; i < 4; ++i) {
            int ml = wm + i*16 + q15;
            #pragma unroll
            for (int j = 0; j < 4; ++j) {
                int nl = wn + j*16 + quad*4;
                float4 b4 = *(const float4*)(bias + n0 + nl);
                f32x4 v = acc[i][j];
                uint2 u;
                u.x = pkbf((v.x + b4.x)*qs, (v.y + b4.y)*qs);
                u.y = pkbf((v.z + b4.z)*qs, (v.w + b4.w)*qs);
                *(uint2*)&sm.Ct[ml*132 + nl] = u;
            }
        }
    } else {
        #pragma unroll
        for (int i = 0; i < 4; ++i) {
            int ml = wm + i*16 + quad*4;
            int sg = m0 + ml;
            int b2 = sg >> 11, s0g = sg & 2047;
            float4 mk4 = *(const float4*)(mask + (size_t)b2*S_LEN + s0g);
            #pragma unroll
            for (int j = 0; j < 4; ++j) {
                int nl = wn + j*16 + q15;
                float bv = bias[n0 + nl];
                f32x4 v = acc[i][j];
                uint2 u;
                u.x = pkbf((v.x + bv)*mk4.x, (v.y + bv)*mk4.y);
                u.y = pkbf((v.z + bv)*mk4.z, (v.w + bv)*mk4.w);
                *(uint2*)&sm.Ct[nl*132 + ml] = u;
            }
        }
    }
    __syncthreads();

    {
        int row  = tid >> 1;
        int half = (tid & 1) * 64;
        const uint4* src = (const uint4*)&sm.Ct[row*132 + half];
        unsigned short* dst;
        if (z < 2) {
            unsigned short* outp = (z == 0) ? qw : kw;
            int mg = m0 + row;  int b2 = mg >> 11, s = mg & 2047;
            int n  = n0 + half; int hh = n >> 6;
            dst = outp + (((size_t)b2*NH + hh)*S_LEN + s)*DHEAD;
        } else {
            int n  = n0 + row;  int hh = n >> 6, dv = n & 63;
            int b2 = m0 >> 11, s0 = m0 & 2047;
            dst = vt + (((size_t)b2*NH + hh)*DHEAD + dv)*S_LEN + s0 + half;
        }
        #pragma unroll
        for (int c = 0; c < 8; ++c) ((uint4*)dst)[c] = src[c];
    }
}

// ---------------------------------------------------------------------------
// Attention: block = 128 queries x (h, b); 512 threads = 8 waves x 16 queries
// (2 blocks/CU -> 16 waves/CU). K staged with permuted rows lambda(key) so
// the QK C-layout, exp'd and packed, IS the PV A-fragment in registers.
//   lambda(key) = (key&32) + ((key>>2)&1)*16 + ((key>>3)&3)*4 + (key&3)
// Q pre-scaled by QSCALE -> v_exp_f32 directly. V pre-multiplied by mask;
// denominator = P @ mask via MFMA. Double-buffered LDS, 1 barrier/tile.
// ---------------------------------------------------------------------------
__global__ __launch_bounds__(512, 4) void attn_mfma(
    const unsigned short* __restrict__ qw, const unsigned short* __restrict__ kw,
    const unsigned short* __restrict__ vt, const unsigned short* __restrict__ mbf,
    float* __restrict__ out)
{
    __shared__ __align__(16) unsigned short Ks[2][64][72];   // [perm key][d]
    __shared__ __align__(16) unsigned short Vs[2][64][72];   // [dv][key]
    __shared__ __align__(16) unsigned short Ms[2][72];       // mask bf16

    const int tid  = threadIdx.x;
    const int lane = tid & 63;
    const int wv   = tid >> 6;          // 0..7
    const int q15  = lane & 15;
    const int quad = lane >> 4;
    const int q0   = blockIdx.x * 128;
    const int h    = blockIdx.y;
    const int b    = blockIdx.z;

    const size_t headoff = ((size_t)b * NH + h) * S_LEN * DHEAD;
    const unsigned short* qb = qw + headoff;
    const unsigned short* kb = kw + headoff;
    const unsigned short* vb = vt + headoff;          // [dv][s]
    const unsigned short* mb = mbf + (size_t)b * S_LEN;

    // Q fragments (B-operand): B[k=d at quad*8+j][n=query at lane&15]
    const unsigned short* qr = qb + (size_t)(q0 + wv*16 + q15)*DHEAD;
    bf16x8 qf0 = *(const bf16x8*)(qr + quad*8);
    bf16x8 qf1 = *(const bf16x8*)(qr + 32 + quad*8);

    const int srow = tid >> 3;          // 0..63 (key row / dv row)
    const int scol = (tid & 7) * 8;     // 0..56
    const int prow = (srow & 32) + ((srow >> 2) & 1) * 16
                   + ((srow >> 3) & 3) * 4 + (srow & 3);

    f32x4 zero4 = {0.f, 0.f, 0.f, 0.f};
    f32x4 oacc[4];
    f32x4 dacc = zero4;
    #pragma unroll
    for (int nj = 0; nj < 4; ++nj) oacc[nj] = zero4;

    // prologue: prefetch tile 0 into registers
    uint4 kr, vr, mr = {0,0,0,0};
    kr = *(const uint4*)(kb + (size_t)srow*DHEAD + scol);
    vr = *(const uint4*)(vb + (size_t)srow*S_LEN + scol);
    if (tid < 8) mr = *(const uint4*)(mb + tid*8);

    for (int t = 0; t < 32; ++t) {
        const int buf = t & 1;
        const int k0  = t * 64;
        // commit staged regs to LDS[buf]
        *(uint4*)&Ks[buf][prow][scol] = kr;
        *(uint4*)&Vs[buf][srow][scol] = vr;
        if (tid < 8) *(uint4*)&Ms[buf][tid*8] = mr;
        // issue prefetch for tile t+1 (clamped; overlaps compute below)
        const int kn = (t < 31) ? k0 + 64 : 0;
        kr = *(const uint4*)(kb + (size_t)(kn + srow)*DHEAD + scol);
        vr = *(const uint4*)(vb + (size_t)srow*S_LEN + kn + scol);
        if (tid < 8) mr = *(const uint4*)(mb + kn + tid*8);
        __syncthreads();

        // ---- QK^T: tile ks reg r = key quad*8+r+4*(ks&1)+32*(ks>>1) ----
        f32x4 s[4];
        #pragma unroll
        for (int ks = 0; ks < 4; ++ks) {
            bf16x8 kf0 = *(const bf16x8*)&Ks[buf][ks*16 + q15][quad*8];
            bf16x8 kf1 = *(const bf16x8*)&Ks[buf][ks*16 + q15][32 + quad*8];
            f32x4 a = MFMA16(kf0, qf0, zero4);
            s[ks] = MFMA16(kf1, qf1, a);
        }
        // ---- exp2 + pack: registers ARE the PV A-fragments ----
        uint4 u0, u1;
        u0.x = pkbf(EXP2F(s[0][0]), EXP2F(s[0][1]));
        u0.y = pkbf(EXP2F(s[0][2]), EXP2F(s[0][3]));
        u0.z = pkbf(EXP2F(s[1][0]), EXP2F(s[1][1]));
        u0.w = pkbf(EXP2F(s[1][2]), EXP2F(s[1][3]));
        u1.x = pkbf(EXP2F(s[2][0]), EXP2F(s[2][1]));
        u1.y = pkbf(EXP2F(s[2][2]), EXP2F(s[2][3]));
        u1.z = pkbf(EXP2F(s[3][0]), EXP2F(s[3][1]));
        u1.w = pkbf(EXP2F(s[3][2]), EXP2F(s[3][3]));
        union { uint4 u; bf16x8 h; } c0, c1;
        c0.u = u0; c1.u = u1;
        bf16x8 pf0 = c0.h;   // keys quad*8+0..7
        bf16x8 pf1 = c1.h;   // keys 32+quad*8+0..7
        // ---- denominator: P @ mask ----
        bf16x8 mf0 = *(const bf16x8*)&Ms[buf][quad*8];
        bf16x8 mf1 = *(const bf16x8*)&Ms[buf][32 + quad*8];
        dacc = MFMA16(pf0, mf0, dacc);
        dacc = MFMA16(pf1, mf1, dacc);
        // ---- PV: V' rows (already mask-scaled) from LDS ----
        #pragma unroll
        for (int nj = 0; nj < 4; ++nj) {
            bf16x8 vf0 = *(const bf16x8*)&Vs[buf][nj*16 + q15][quad*8];
            bf16x8 vf1 = *(const bf16x8*)&Vs[buf][nj*16 + q15][32 + quad*8];
            oacc[nj] = MFMA16(pf0, vf0, oacc[nj]);
            oacc[nj] = MFMA16(pf1, vf1, oacc[nj]);
        }
    }

    // epilogue: D rows quad*4+r = query; denom replicated across n lanes
    #pragma unroll
    for (int r = 0; r < 4; ++r) {
        float inv = 1.0f / (dacc[r] + 1e-8f);
        size_t row = ((size_t)b*S_LEN + q0 + wv*16 + quad*4 + r)*DMODEL + h*DHEAD;
        #pragma unroll
        for (int nj = 0; nj < 4; ++nj)
            out[row + nj*16 + q15] = oacc[nj][r] * inv;
    }
}

// ---------------------------------------------------------------------------
extern "C" void kernel_launch(void* const* d_in, const int* in_sizes, int n_in,
                              void* d_out, int out_size, void* d_ws, size_t ws_size,
                              hipStream_t stream) {
    const float* Q    = (const float*)d_in[0];
    const float* msk  = (const float*)d_in[1];
    const float* W_Q  = (const float*)d_in[2];
    const float* b_Q  = (const float*)d_in[3];
    const float* W_K  = (const float*)d_in[4];
    const float* b_K  = (const float*)d_in[5];
    const float* W_V  = (const float*)d_in[6];
    const float* b_V  = (const float*)d_in[7];
    float* out = (float*)d_out;

    unsigned short* wsu = (unsigned short*)d_ws;
    unsigned short* Qbf = wsu;                                   // 4M elems
    unsigned short* Wbf = Qbf + (size_t)4096*1024;               // 3M
    unsigned short* qwb = Wbf + (size_t)3*1024*1024;             // 4M
    unsigned short* kwb = qwb + (size_t)4*1024*1024;             // 4M
    unsigned short* vtb = kwb + (size_t)4*1024*1024;             // 4M
    unsigned short* mbf = vtb + (size_t)4*1024*1024;             // 4K

    cvt_all<<<3586, 256, 0, stream>>>(Q, W_Q, W_K, W_V, msk, Qbf, Wbf, mbf);

    proj_mfma<<<dim3(8, 32, 3), 256, 0, stream>>>(
        Qbf, Wbf, b_Q, b_K, b_V, msk, qwb, kwb, vtb);

    attn_mfma<<<dim3(S_LEN/128, NH, BATCH), 512, 0, stream>>>(
        qwb, kwb, vtb, mbf, out);
}

// Round 9
// 189.882 us; speedup vs baseline: 1.0028x; 1.0028x over previous
//
#include <hip/hip_runtime.h>
#include <hip/hip_bf16.h>
#include <math.h>

#define BATCH  2
#define S_LEN  2048
#define DMODEL 1024
#define NH     16
#define DHEAD  64

typedef __attribute__((ext_vector_type(8))) short bf16x8;   // 8 bf16 = 4 VGPRs
typedef __attribute__((ext_vector_type(4))) float f32x4;

#define MFMA16(a,b,c) __builtin_amdgcn_mfma_f32_16x16x32_bf16((a),(b),(c),0,0,0)

// Q pre-scale: (1/sqrt(64)) * log2(e) so attention uses exp2 directly
#define QSCALE 0.18033688011110793f
#define EXP2F(x) __builtin_amdgcn_exp2f(x)

__device__ __forceinline__ unsigned int pkbf(float a, float b) {
    __hip_bfloat162 h = __float22bfloat162_rn(make_float2(a, b));
    union { __hip_bfloat162 h; unsigned int u; } v; v.h = h; return v.u;
}
__device__ __forceinline__ void gl2lds16(const void* g, void* l) {
    __builtin_amdgcn_global_load_lds(
        (const __attribute__((address_space(1))) void*)(g),
        (__attribute__((address_space(3))) void*)(l), 16, 0, 0);
}

// ---------------------------------------------------------------------------
// Single fused fp32->bf16 convert for Q, W_Q|W_K|W_V, mask. 8 elems/unit.
// ---------------------------------------------------------------------------
__global__ __launch_bounds__(256) void cvt_all(
    const float* __restrict__ Q,  const float* __restrict__ WQ,
    const float* __restrict__ WK, const float* __restrict__ WV,
    const float* __restrict__ msk,
    unsigned short* __restrict__ Qbf, unsigned short* __restrict__ Wbf,
    unsigned short* __restrict__ mbf)
{
    int i = blockIdx.x * blockDim.x + threadIdx.x;   // grid covers 918016 units
    const float* src;
    unsigned short* dst;
    int off;
    if (i < 524288) {
        src = Q; dst = Qbf; off = i;
    } else if (i < 917504) {
        int j = i - 524288;                  // [0, 393216)
        int which = j >> 17;                 // /131072
        src = (which == 0) ? WQ : ((which == 1) ? WK : WV);
        dst = Wbf + ((size_t)which << 20);   // which * 1048576
        off = j & 131071;
    } else {
        int j = i - 917504;
        if (j >= 512) return;
        src = msk; dst = mbf; off = j;
    }
    float4 a = ((const float4*)src)[2*off];
    float4 b = ((const float4*)src)[2*off + 1];
    uint4 o;
    o.x = pkbf(a.x, a.y); o.y = pkbf(a.z, a.w);
    o.z = pkbf(b.x, b.y); o.w = pkbf(b.z, b.w);
    ((uint4*)dst)[off] = o;
}

// ---------------------------------------------------------------------------
// Projection GEMM with folds:
//   z=0 -> qw [b,h,s,dk], scaled by QSCALE; z=1 -> kw; z=2 -> vt [b,h,dv,s]
//   with V' = mask*V.
// 128x128 tile, BK=32, 4 waves. K-loop: global_load_lds DMA, double-buffered
// LDS, ONE barrier per iteration: barrier -> issue DMA(t+1 -> buf^1) ->
// compute buf. DMA has the full compute phase in flight before the next
// barrier's vmcnt(0) drain. Epilogue through LDS (aliases staging).
// ---------------------------------------------------------------------------
__global__ __launch_bounds__(256) void proj_mfma(
    const unsigned short* __restrict__ Abf,   // [4096][1024]
    const unsigned short* __restrict__ Wbf,   // [3][1024][1024]
    const float* __restrict__ bQ, const float* __restrict__ bK,
    const float* __restrict__ bV, const float* __restrict__ mask,
    unsigned short* __restrict__ qw, unsigned short* __restrict__ kw,
    unsigned short* __restrict__ vt)
{
    __shared__ union {
        struct { unsigned short A[2][4096]; unsigned short B[2][4096]; } s; // 32KB
        unsigned short Ct[128*132];                                         // 33.8KB
    } sm;

    const int tid  = threadIdx.x;
    const int lane = tid & 63;
    const int wv   = tid >> 6;
    const int wm   = (wv >> 1) * 64;
    const int wn   = (wv & 1) * 64;
    const int q15  = lane & 15;
    const int quad = lane >> 4;
    const int z    = blockIdx.z;
    const int n0   = blockIdx.x * 128;
    const int m0   = blockIdx.y * 128;

    const unsigned short* Wz = Wbf + (size_t)z * DMODEL * DMODEL;
    const float* bias = (z == 0) ? bQ : ((z == 1) ? bK : bV);

    // staging map: tile = 8KB; thread covers byte offsets tid*16 and +4096.
    const int o0 = tid * 16;             // byte offset in tile
    const int r0 = o0 >> 6,  cc0 = (o0 & 63) >> 1;   // row, short-col
    const int o1 = o0 + 4096;
    const int r1 = o1 >> 6,  cc1 = (o1 & 63) >> 1;

    f32x4 zero4 = {0.f, 0.f, 0.f, 0.f};
    f32x4 acc[4][4];
    #pragma unroll
    for (int i = 0; i < 4; ++i)
        #pragma unroll
        for (int j = 0; j < 4; ++j) acc[i][j] = zero4;

    // prologue: DMA tile 0 into buf 0
    gl2lds16(Abf + (size_t)(m0 + r0)*DMODEL + cc0, (char*)sm.s.A[0] + o0);
    gl2lds16(Abf + (size_t)(m0 + r1)*DMODEL + cc1, (char*)sm.s.A[0] + o1);
    gl2lds16(Wz  + (size_t)(n0 + r0)*DMODEL + cc0, (char*)sm.s.B[0] + o0);
    gl2lds16(Wz  + (size_t)(n0 + r1)*DMODEL + cc1, (char*)sm.s.B[0] + o1);

    for (int t = 0; t < 32; ++t) {
        const int buf = t & 1;
        __syncthreads();   // tile t landed (vmcnt drained); buf^1 readers done
        if (t < 31) {
            const int kn = (t + 1) * 32;
            gl2lds16(Abf + (size_t)(m0 + r0)*DMODEL + kn + cc0, (char*)sm.s.A[buf^1] + o0);
            gl2lds16(Abf + (size_t)(m0 + r1)*DMODEL + kn + cc1, (char*)sm.s.A[buf^1] + o1);
            gl2lds16(Wz  + (size_t)(n0 + r0)*DMODEL + kn + cc0, (char*)sm.s.B[buf^1] + o0);
            gl2lds16(Wz  + (size_t)(n0 + r1)*DMODEL + kn + cc1, (char*)sm.s.B[buf^1] + o1);
        }

        bf16x8 af[4], bf[4];
        #pragma unroll
        for (int i = 0; i < 4; ++i)
            af[i] = *(const bf16x8*)(sm.s.A[buf] + (wm + i*16 + q15) * 32 + quad * 8);
        #pragma unroll
        for (int j = 0; j < 4; ++j)
            bf[j] = *(const bf16x8*)(sm.s.B[buf] + (wn + j*16 + q15) * 32 + quad * 8);

        if (z < 2) {
            #pragma unroll
            for (int i = 0; i < 4; ++i)
                #pragma unroll
                for (int j = 0; j < 4; ++j)
                    acc[i][j] = MFMA16(bf[j], af[i], acc[i][j]);
        } else {
            #pragma unroll
            for (int i = 0; i < 4; ++i)
                #pragma unroll
                for (int j = 0; j < 4; ++j)
                    acc[i][j] = MFMA16(af[i], bf[j], acc[i][j]);
        }
    }

    __syncthreads();   // all compute reads done; Ct aliases staging

    if (z < 2) {
        const float qs = (z == 0) ? QSCALE : 1.0f;
        #pragma unroll
        for (int i = 0; i < 4; ++i) {
            int ml = wm + i*16 + q15;
            #pragma unroll
            for (int j = 0; j < 4; ++j) {
                int nl = wn + j*16 + quad*4;
                float4 b4 = *(const float4*)(bias + n0 + nl);
                f32x4 v = acc[i][j];
                uint2 u;
                u.x = pkbf((v.x + b4.x)*qs, (v.y + b4.y)*qs);
                u.y = pkbf((v.z + b4.z)*qs, (v.w + b4.w)*qs);
                *(uint2*)&sm.Ct[ml*132 + nl] = u;
            }
        }
    } else {
        #pragma unroll
        for (int i = 0; i < 4; ++i) {
            int ml = wm + i*16 + quad*4;
            int sg = m0 + ml;
            int b2 = sg >> 11, s0g = sg & 2047;
            float4 mk4 = *(const float4*)(mask + (size_t)b2*S_LEN + s0g);
            #pragma unroll
            for (int j = 0; j < 4; ++j) {
                int nl = wn + j*16 + q15;
                float bv = bias[n0 + nl];
                f32x4 v = acc[i][j];
                uint2 u;
                u.x = pkbf((v.x + bv)*mk4.x, (v.y + bv)*mk4.y);
                u.y = pkbf((v.z + bv)*mk4.z, (v.w + bv)*mk4.w);
                *(uint2*)&sm.Ct[nl*132 + ml] = u;
            }
        }
    }
    __syncthreads();

    {
        int row  = tid >> 1;
        int half = (tid & 1) * 64;
        const uint4* src = (const uint4*)&sm.Ct[row*132 + half];
        unsigned short* dst;
        if (z < 2) {
            unsigned short* outp = (z == 0) ? qw : kw;
            int mg = m0 + row;  int b2 = mg >> 11, s = mg & 2047;
            int n  = n0 + half; int hh = n >> 6;
            dst = outp + (((size_t)b2*NH + hh)*S_LEN + s)*DHEAD;
        } else {
            int n  = n0 + row;  int hh = n >> 6, dv = n & 63;
            int b2 = m0 >> 11, s0 = m0 & 2047;
            dst = vt + (((size_t)b2*NH + hh)*DHEAD + dv)*S_LEN + s0 + half;
        }
        #pragma unroll
        for (int c = 0; c < 8; ++c) ((uint4*)dst)[c] = src[c];
    }
}

// ---------------------------------------------------------------------------
// Attention: block = 64 queries x (h, b); 256 threads = 4 waves x 16 queries.
// Grid 1024 = 4 blocks/CU (16 waves/CU). K staged with permuted rows
//   lambda(key) = (key&32) + ((key>>2)&1)*16 + ((key>>3)&3)*4 + (key&3)
// so the QK C-layout, exp'd and packed, IS the PV A-fragment in registers.
// Q pre-scaled by QSCALE -> v_exp_f32 directly. V pre-multiplied by mask;
// denominator = P @ mask via MFMA. Double-buffered LDS, 1 barrier/tile.
// ---------------------------------------------------------------------------
__global__ __launch_bounds__(256, 4) void attn_mfma(
    const unsigned short* __restrict__ qw, const unsigned short* __restrict__ kw,
    const unsigned short* __restrict__ vt, const unsigned short* __restrict__ mbf,
    float* __restrict__ out)
{
    __shared__ __align__(16) unsigned short Ks[2][64][72];   // [perm key][d]
    __shared__ __align__(16) unsigned short Vs[2][64][72];   // [dv][key]
    __shared__ __align__(16) unsigned short Ms[2][72];       // mask bf16

    const int tid  = threadIdx.x;
    const int lane = tid & 63;
    const int wv   = tid >> 6;          // 0..3
    const int q15  = lane & 15;
    const int quad = lane >> 4;
    const int q0   = blockIdx.x * 64;
    const int h    = blockIdx.y;
    const int b    = blockIdx.z;

    const size_t headoff = ((size_t)b * NH + h) * S_LEN * DHEAD;
    const unsigned short* qb = qw + headoff;
    const unsigned short* kb = kw + headoff;
    const unsigned short* vb = vt + headoff;          // [dv][s]
    const unsigned short* mb = mbf + (size_t)b * S_LEN;

    // Q fragments (B-operand): B[k=d at quad*8+j][n=query at lane&15]
    const unsigned short* qr = qb + (size_t)(q0 + wv*16 + q15)*DHEAD;
    bf16x8 qf0 = *(const bf16x8*)(qr + quad*8);
    bf16x8 qf1 = *(const bf16x8*)(qr + 32 + quad*8);

    const int srow = tid >> 3;          // 0..31 (key row / dv row; +32 second)
    const int scol = (tid & 7) * 8;     // 0..56
    const int prow = ((srow >> 2) & 1) * 16 + ((srow >> 3) & 3) * 4 + (srow & 3);

    f32x4 zero4 = {0.f, 0.f, 0.f, 0.f};
    f32x4 oacc[4];
    f32x4 dacc = zero4;
    #pragma unroll
    for (int nj = 0; nj < 4; ++nj) oacc[nj] = zero4;

    // prologue: prefetch tile 0 into registers
    uint4 kr0, kr1, vr0, vr1, mr = {0,0,0,0};
    kr0 = *(const uint4*)(kb + (size_t)(srow)     *DHEAD + scol);
    kr1 = *(const uint4*)(kb + (size_t)(srow + 32)*DHEAD + scol);
    vr0 = *(const uint4*)(vb + (size_t)(srow)     *S_LEN + scol);
    vr1 = *(const uint4*)(vb + (size_t)(srow + 32)*S_LEN + scol);
    if (tid < 8) mr = *(const uint4*)(mb + tid*8);

    for (int t = 0; t < 32; ++t) {
        const int buf = t & 1;
        const int k0  = t * 64;
        // commit staged regs to LDS[buf]
        *(uint4*)&Ks[buf][prow][scol]      = kr0;
        *(uint4*)&Ks[buf][prow + 32][scol] = kr1;
        *(uint4*)&Vs[buf][srow][scol]      = vr0;
        *(uint4*)&Vs[buf][srow + 32][scol] = vr1;
        if (tid < 8) *(uint4*)&Ms[buf][tid*8] = mr;
        // issue prefetch for tile t+1 (clamped; overlaps compute below)
        const int kn = (t < 31) ? k0 + 64 : 0;
        kr0 = *(const uint4*)(kb + (size_t)(kn + srow)     *DHEAD + scol);
        kr1 = *(const uint4*)(kb + (size_t)(kn + srow + 32)*DHEAD + scol);
        vr0 = *(const uint4*)(vb + (size_t)(srow)     *S_LEN + kn + scol);
        vr1 = *(const uint4*)(vb + (size_t)(srow + 32)*S_LEN + kn + scol);
        if (tid < 8) mr = *(const uint4*)(mb + kn + tid*8);
        __syncthreads();

        // ---- QK^T: tile ks reg r = key quad*8+r+4*(ks&1)+32*(ks>>1) ----
        f32x4 s[4];
        #pragma unroll
        for (int ks = 0; ks < 4; ++ks) {
            bf16x8 kf0 = *(const bf16x8*)&Ks[buf][ks*16 + q15][quad*8];
            bf16x8 kf1 = *(const bf16x8*)&Ks[buf][ks*16 + q15][32 + quad*8];
            f32x4 a = MFMA16(kf0, qf0, zero4);
            s[ks] = MFMA16(kf1, qf1, a);
        }
        // ---- exp2 + pack: registers ARE the PV A-fragments ----
        uint4 u0, u1;
        u0.x = pkbf(EXP2F(s[0][0]), EXP2F(s[0][1]));
        u0.y = pkbf(EXP2F(s[0][2]), EXP2F(s[0][3]));
        u0.z = pkbf(EXP2F(s[1][0]), EXP2F(s[1][1]));
        u0.w = pkbf(EXP2F(s[1][2]), EXP2F(s[1][3]));
        u1.x = pkbf(EXP2F(s[2][0]), EXP2F(s[2][1]));
        u1.y = pkbf(EXP2F(s[2][2]), EXP2F(s[2][3]));
        u1.z = pkbf(EXP2F(s[3][0]), EXP2F(s[3][1]));
        u1.w = pkbf(EXP2F(s[3][2]), EXP2F(s[3][3]));
        union { uint4 u; bf16x8 h; } c0, c1;
        c0.u = u0; c1.u = u1;
        bf16x8 pf0 = c0.h;   // keys quad*8+0..7
        bf16x8 pf1 = c1.h;   // keys 32+quad*8+0..7
        // ---- denominator: P @ mask ----
        bf16x8 mf0 = *(const bf16x8*)&Ms[buf][quad*8];
        bf16x8 mf1 = *(const bf16x8*)&Ms[buf][32 + quad*8];
        dacc = MFMA16(pf0, mf0, dacc);
        dacc = MFMA16(pf1, mf1, dacc);
        // ---- PV: V' rows (already mask-scaled) from LDS ----
        #pragma unroll
        for (int nj = 0; nj < 4; ++nj) {
            bf16x8 vf0 = *(const bf16x8*)&Vs[buf][nj*16 + q15][quad*8];
            bf16x8 vf1 = *(const bf16x8*)&Vs[buf][nj*16 + q15][32 + quad*8];
            oacc[nj] = MFMA16(pf0, vf0, oacc[nj]);
            oacc[nj] = MFMA16(pf1, vf1, oacc[nj]);
        }
    }

    // epilogue: D rows quad*4+r = query; denom replicated across n lanes
    #pragma unroll
    for (int r = 0; r < 4; ++r) {
        float inv = 1.0f / (dacc[r] + 1e-8f);
        size_t row = ((size_t)b*S_LEN + q0 + wv*16 + quad*4 + r)*DMODEL + h*DHEAD;
        #pragma unroll
        for (int nj = 0; nj < 4; ++nj)
            out[row + nj*16 + q15] = oacc[nj][r] * inv;
    }
}

// ---------------------------------------------------------------------------
extern "C" void kernel_launch(void* const* d_in, const int* in_sizes, int n_in,
                              void* d_out, int out_size, void* d_ws, size_t ws_size,
                              hipStream_t stream) {
    const float* Q    = (const float*)d_in[0];
    const float* msk  = (const float*)d_in[1];
    const float* W_Q  = (const float*)d_in[2];
    const float* b_Q  = (const float*)d_in[3];
    const float* W_K  = (const float*)d_in[4];
    const float* b_K  = (const float*)d_in[5];
    const float* W_V  = (const float*)d_in[6];
    const float* b_V  = (const float*)d_in[7];
    float* out = (float*)d_out;

    unsigned short* wsu = (unsigned short*)d_ws;
    unsigned short* Qbf = wsu;                                   // 4M elems
    unsigned short* Wbf = Qbf + (size_t)4096*1024;               // 3M
    unsigned short* qwb = Wbf + (size_t)3*1024*1024;             // 4M
    unsigned short* kwb = qwb + (size_t)4*1024*1024;             // 4M
    unsigned short* vtb = kwb + (size_t)4*1024*1024;             // 4M
    unsigned short* mbf = vtb + (size_t)4*1024*1024;             // 4K

    cvt_all<<<3586, 256, 0, stream>>>(Q, W_Q, W_K, W_V, msk, Qbf, Wbf, mbf);

    proj_mfma<<<dim3(8, 32, 3), 256, 0, stream>>>(
        Qbf, Wbf, b_Q, b_K, b_V, msk, qwb, kwb, vtb);

    attn_mfma<<<dim3(S_LEN/64, NH, BATCH), 256, 0, stream>>>(
        qwb, kwb, vtb, mbf, out);
}